// Round 1
// baseline (181.305 us; speedup 1.0000x reference)
//
#include <hip/hip_runtime.h>
#include <hip/hip_bf16.h>

// Problem constants (reference: B,H,I,E = 16,16,512,512)
#define B_ 16
#define H_ 16
#define I_ 512
#define E_ 512

// ---------------------------------------------------------------------------
// Kernel 1: emb[b,h,e] = sum_i x[b,i,e] * W_v[h,i,e]
// (softmax over axis=2 followed by sum over axis=2 collapses attention away)
//
// Tiling: each block covers BG=4 b's, HG=4 h's, EC=64 e's, with the i-loop
// split IS=4 ways across the block's waves, reduced through LDS.
// Grid: (E/EC=8, B/BG=4, H/HG=4) = 128 blocks, 256 threads.
// x and W_v are each logically read (16/BG)=4x -> 128 MB total via L2/L3.
// ---------------------------------------------------------------------------
#define BG 4
#define HG 4
#define EC 64
#define IS 4

__global__ __launch_bounds__(256) void k_emb(const float* __restrict__ x,
                                             const float* __restrict__ Wv,
                                             float* __restrict__ emb) {
    const int e0 = blockIdx.x * EC;
    const int b0 = blockIdx.y * BG;
    const int h0 = blockIdx.z * HG;
    const int lane_e = threadIdx.x & 63;   // 0..63
    const int is     = threadIdx.x >> 6;   // 0..3
    const int e      = e0 + lane_e;

    float acc[BG][HG];
#pragma unroll
    for (int bi = 0; bi < BG; ++bi)
#pragma unroll
        for (int hj = 0; hj < HG; ++hj) acc[bi][hj] = 0.0f;

    // per-(b)/(h) base offsets at i=0
    const float* xp[BG];
    const float* wp[HG];
#pragma unroll
    for (int bi = 0; bi < BG; ++bi) xp[bi] = x  + ((size_t)(b0 + bi) * I_) * E_ + e;
#pragma unroll
    for (int hj = 0; hj < HG; ++hj) wp[hj] = Wv + ((size_t)(h0 + hj) * I_) * E_ + e;

    const int ibeg = is * (I_ / IS);
    const int iend = ibeg + (I_ / IS);
    for (int i = ibeg; i < iend; ++i) {
        float xv[BG], wv[HG];
        const int off = i * E_;
#pragma unroll
        for (int bi = 0; bi < BG; ++bi) xv[bi] = xp[bi][off];
#pragma unroll
        for (int hj = 0; hj < HG; ++hj) wv[hj] = wp[hj][off];
#pragma unroll
        for (int bi = 0; bi < BG; ++bi)
#pragma unroll
            for (int hj = 0; hj < HG; ++hj)
                acc[bi][hj] = fmaf(xv[bi], wv[hj], acc[bi][hj]);
    }

    // reduce the IS=4 i-slices through LDS
    __shared__ float red[IS][BG * HG][EC];  // 4*16*64*4B = 16 KB
#pragma unroll
    for (int bi = 0; bi < BG; ++bi)
#pragma unroll
        for (int hj = 0; hj < HG; ++hj)
            red[is][bi * HG + hj][lane_e] = acc[bi][hj];
    __syncthreads();

    // 16*64 = 1024 outputs, 256 threads -> 4 each
    for (int t = threadIdx.x; t < BG * HG * EC; t += 256) {
        const int pair = t >> 6;   // bi*HG + hj
        const int le   = t & 63;
        float s = red[0][pair][le] + red[1][pair][le] +
                  red[2][pair][le] + red[3][pair][le];
        const int bi = pair >> 2, hj = pair & 3;
        const int row = (b0 + bi) * H_ + (h0 + hj);
        emb[(size_t)row * E_ + e0 + le] = s;
    }
}

// ---------------------------------------------------------------------------
// Kernel 2: out[r, c] = sum_e emb[r, e] * mlp_w[c, e] + mlp_b[c]
// r in [0,256) = b*H+h, c in [0,512). Classic LDS-tiled GEMM:
// 32 (rows) x 32 (cols) tiles, K-chunks of 64, 2x2 micro-tile per thread.
// Grid: (512/32=16, 256/32=8) = 128 blocks, 256 threads.
// ---------------------------------------------------------------------------
#define TM 32
#define TN 32
#define TK 64

__global__ __launch_bounds__(256) void k_mlp(const float* __restrict__ emb,
                                             const float* __restrict__ W,
                                             const float* __restrict__ bias,
                                             float* __restrict__ out) {
    const int cblk = blockIdx.x;  // col tile
    const int rblk = blockIdx.y;  // row tile

    __shared__ float As[TM][TK];  // emb tile  [row][k]   8 KB
    __shared__ float Ws[TN][TK];  // weight tile [col][k] 8 KB

    const int tx = threadIdx.x & 15;   // col group 0..15
    const int ty = threadIdx.x >> 4;   // row group 0..15

    float acc[2][2] = {{0.f, 0.f}, {0.f, 0.f}};

    // loader mapping: thread loads 8 consecutive floats (2x float4)
    const int lrow = threadIdx.x >> 3;        // 0..31
    const int lk   = (threadIdx.x & 7) * 8;   // 0,8,...,56

    for (int k0 = 0; k0 < E_; k0 += TK) {
        // load A tile: emb[rblk*32 + lrow][k0 + lk .. +8]
        {
            const float4* src = (const float4*)(emb + (size_t)(rblk * TM + lrow) * E_ + k0 + lk);
            float4 v0 = src[0], v1 = src[1];
            *(float4*)&As[lrow][lk]     = v0;
            *(float4*)&As[lrow][lk + 4] = v1;
        }
        // load W tile: W[cblk*32 + lrow][k0 + lk .. +8]
        {
            const float4* src = (const float4*)(W + (size_t)(cblk * TN + lrow) * E_ + k0 + lk);
            float4 v0 = src[0], v1 = src[1];
            *(float4*)&Ws[lrow][lk]     = v0;
            *(float4*)&Ws[lrow][lk + 4] = v1;
        }
        __syncthreads();

#pragma unroll
        for (int k = 0; k < TK; ++k) {
            const float a0 = As[ty * 2 + 0][k];
            const float a1 = As[ty * 2 + 1][k];
            const float w0 = Ws[tx * 2 + 0][k];
            const float w1 = Ws[tx * 2 + 1][k];
            acc[0][0] = fmaf(a0, w0, acc[0][0]);
            acc[0][1] = fmaf(a0, w1, acc[0][1]);
            acc[1][0] = fmaf(a1, w0, acc[1][0]);
            acc[1][1] = fmaf(a1, w1, acc[1][1]);
        }
        __syncthreads();
    }

#pragma unroll
    for (int dr = 0; dr < 2; ++dr) {
#pragma unroll
        for (int dc = 0; dc < 2; ++dc) {
            const int r = rblk * TM + ty * 2 + dr;
            const int c = cblk * TN + tx * 2 + dc;
            out[(size_t)r * E_ + c] = acc[dr][dc] + bias[c];
        }
    }
}

extern "C" void kernel_launch(void* const* d_in, const int* in_sizes, int n_in,
                              void* d_out, int out_size, void* d_ws, size_t ws_size,
                              hipStream_t stream) {
    // setup_inputs order: x, W_q, W_k, W_v, mlp_w, mlp_b  (all fp32)
    const float* x     = (const float*)d_in[0];
    const float* W_v   = (const float*)d_in[3];
    const float* mlp_w = (const float*)d_in[4];
    const float* mlp_b = (const float*)d_in[5];
    float* out = (float*)d_out;

    float* emb = (float*)d_ws;  // 256 * 512 * 4 B = 512 KB scratch

    dim3 g1(E_ / EC, B_ / BG, H_ / HG);  // (8,4,4) = 128 blocks
    k_emb<<<g1, 256, 0, stream>>>(x, W_v, emb);

    dim3 g2(E_ / TN, (B_ * H_) / TM);    // (16,8) = 128 blocks
    k_mlp<<<g2, 256, 0, stream>>>(emb, mlp_w, mlp_b, out);
}

// Round 2
// 123.296 us; speedup vs baseline: 1.4705x; 1.4705x over previous
//
#include <hip/hip_runtime.h>
#include <hip/hip_bf16.h>

// Problem constants (reference: B,H,I,E = 16,16,512,512)
#define B_ 16
#define H_ 16
#define I_ 512
#define E_ 512

// Algebraic collapse (verified round 1, absmax 0.125):
//   softmax over axis=2 followed by sum over axis=2 makes attention a no-op:
//   emb[b,h,e] = sum_i x[b,i,e] * W_v[h,i,e];  out = emb @ mlp_w^T + mlp_b.

// ---------------------------------------------------------------------------
// Kernel 1: partial emb. Each block: 4 b's x 4 h's x 128 e's (float2 lanes),
// one of NSLICE=8 i-slices (64 i's, split 16/wave across 4 waves).
// Grid (4, 4, 4*8) = 512 blocks -> 8 waves/CU. Partials to d_ws.
// ---------------------------------------------------------------------------
#define NSLICE 8

__global__ __launch_bounds__(256) void k_emb_part(const float* __restrict__ x,
                                                  const float* __restrict__ Wv,
                                                  float2* __restrict__ part) {
    const int E2 = E_ / 2;                 // 256 float2 per row
    const int e2_0  = blockIdx.x * 64;     // float2 base (128-float e-chunk)
    const int b0    = blockIdx.y * 4;
    const int h0    = (blockIdx.z & 3) * 4;
    const int slice = blockIdx.z >> 2;     // 0..7
    const int lane  = threadIdx.x & 63;
    const int wave  = threadIdx.x >> 6;

    const float2* x2 = (const float2*)x;
    const float2* w2 = (const float2*)Wv;

    float2 acc[4][4];
#pragma unroll
    for (int bi = 0; bi < 4; ++bi)
#pragma unroll
        for (int hj = 0; hj < 4; ++hj) { acc[bi][hj].x = 0.f; acc[bi][hj].y = 0.f; }

    const float2* xp[4];
    const float2* wp[4];
#pragma unroll
    for (int bi = 0; bi < 4; ++bi) xp[bi] = x2 + (size_t)(b0 + bi) * I_ * E2 + e2_0 + lane;
#pragma unroll
    for (int hj = 0; hj < 4; ++hj) wp[hj] = w2 + (size_t)(h0 + hj) * I_ * E2 + e2_0 + lane;

    const int ib = slice * 64 + wave * 16;
    for (int ii = 0; ii < 16; ++ii) {
        const int off = (ib + ii) * E2;
        float2 xv[4], wv[4];
#pragma unroll
        for (int bi = 0; bi < 4; ++bi) xv[bi] = xp[bi][off];
#pragma unroll
        for (int hj = 0; hj < 4; ++hj) wv[hj] = wp[hj][off];
#pragma unroll
        for (int bi = 0; bi < 4; ++bi)
#pragma unroll
            for (int hj = 0; hj < 4; ++hj) {
                acc[bi][hj].x = fmaf(xv[bi].x, wv[hj].x, acc[bi][hj].x);
                acc[bi][hj].y = fmaf(xv[bi].y, wv[hj].y, acc[bi][hj].y);
            }
    }

    // reduce the 4 wave-slices through LDS (stride-1 float2 -> conflict-free)
    __shared__ float2 red[4][16][64];  // 32 KB
#pragma unroll
    for (int bi = 0; bi < 4; ++bi)
#pragma unroll
        for (int hj = 0; hj < 4; ++hj)
            red[wave][bi * 4 + hj][lane] = acc[bi][hj];
    __syncthreads();

    for (int t = threadIdx.x; t < 16 * 64; t += 256) {
        const int pair = t >> 6, le = t & 63;
        float2 s0 = red[0][pair][le], s1 = red[1][pair][le];
        float2 s2 = red[2][pair][le], s3 = red[3][pair][le];
        float2 s; s.x = (s0.x + s1.x) + (s2.x + s3.x); s.y = (s0.y + s1.y) + (s2.y + s3.y);
        const int row = (b0 + (pair >> 2)) * H_ + h0 + (pair & 3);
        part[((size_t)slice * (B_ * H_) + row) * E2 + e2_0 + le] = s;
    }
}

// ---------------------------------------------------------------------------
// Kernel 2: emb = sum over NSLICE partial slices. float4 lanes.
// 256*512 floats = 32768 float4 -> 128 blocks x 256 threads.
// ---------------------------------------------------------------------------
__global__ __launch_bounds__(256) void k_reduce(const float4* __restrict__ part,
                                                float4* __restrict__ emb) {
    const int idx = blockIdx.x * 256 + threadIdx.x;  // < 32768
    const int sl_stride = (B_ * H_ * E_) / 4;        // 32768 float4 per slice
    float4 s = part[idx];
#pragma unroll
    for (int sl = 1; sl < NSLICE; ++sl) {
        float4 p = part[sl * sl_stride + idx];
        s.x += p.x; s.y += p.y; s.z += p.z; s.w += p.w;
    }
    emb[idx] = s;
}

// ---------------------------------------------------------------------------
// Kernel 3: out[r,c] = sum_e emb[r,e]*W[c,e] + bias[c].
// 16x32 output tile, K-chunks of 64. LDS tiles stored TRANSPOSED with +1 pad
// so inner-loop reads are broadcast/consecutive (no 16-way bank conflicts).
// Grid (16,16) = 256 blocks.
// ---------------------------------------------------------------------------
#define MT 16
#define NT 32
#define KT 64

__global__ __launch_bounds__(256) void k_mlp(const float* __restrict__ emb,
                                             const float* __restrict__ W,
                                             const float* __restrict__ bias,
                                             float* __restrict__ out) {
    const int cblk = blockIdx.x;  // 0..15
    const int rblk = blockIdx.y;  // 0..15

    __shared__ float As[KT][MT + 1];  // [k][row], 4.25 KB
    __shared__ float Ws[KT][NT + 1];  // [k][col], 8.25 KB

    const int tx = threadIdx.x & 15;  // col pair 0..15
    const int ty = threadIdx.x >> 4;  // row 0..15

    float acc0 = 0.f, acc1 = 0.f;

    // loader mappings (all float4 global reads, coalesced)
    const int alr = threadIdx.x >> 4;        // A row 0..15
    const int alk = (threadIdx.x & 15) * 4;  // A k 0..60
    const int wlr = threadIdx.x >> 3;        // W col 0..31
    const int wlk = (threadIdx.x & 7) * 8;   // W k 0..56

    for (int k0 = 0; k0 < E_; k0 += KT) {
        float4 a = *(const float4*)(emb + (size_t)(rblk * MT + alr) * E_ + k0 + alk);
        As[alk + 0][alr] = a.x; As[alk + 1][alr] = a.y;
        As[alk + 2][alr] = a.z; As[alk + 3][alr] = a.w;

        const float* wsrc = W + (size_t)(cblk * NT + wlr) * E_ + k0 + wlk;
        float4 w0 = *(const float4*)wsrc;
        float4 w1 = *(const float4*)(wsrc + 4);
        Ws[wlk + 0][wlr] = w0.x; Ws[wlk + 1][wlr] = w0.y;
        Ws[wlk + 2][wlr] = w0.z; Ws[wlk + 3][wlr] = w0.w;
        Ws[wlk + 4][wlr] = w1.x; Ws[wlk + 5][wlr] = w1.y;
        Ws[wlk + 6][wlr] = w1.z; Ws[wlk + 7][wlr] = w1.w;
        __syncthreads();

#pragma unroll
        for (int k = 0; k < KT; ++k) {
            const float a0 = As[k][ty];          // 4 addrs/wave, 16-way broadcast
            const float w0 = Ws[k][tx * 2 + 0];  // consecutive pair -> b64 read
            const float w1 = Ws[k][tx * 2 + 1];
            acc0 = fmaf(a0, w0, acc0);
            acc1 = fmaf(a0, w1, acc1);
        }
        __syncthreads();
    }

    const int r = rblk * MT + ty;
    const int c = cblk * NT + tx * 2;
    out[(size_t)r * E_ + c + 0] = acc0 + bias[c + 0];
    out[(size_t)r * E_ + c + 1] = acc1 + bias[c + 1];
}

extern "C" void kernel_launch(void* const* d_in, const int* in_sizes, int n_in,
                              void* d_out, int out_size, void* d_ws, size_t ws_size,
                              hipStream_t stream) {
    // setup_inputs order: x, W_q, W_k, W_v, mlp_w, mlp_b  (all fp32)
    const float* x     = (const float*)d_in[0];
    const float* W_v   = (const float*)d_in[3];
    const float* mlp_w = (const float*)d_in[4];
    const float* mlp_b = (const float*)d_in[5];
    float* out = (float*)d_out;

    // workspace: partials (8 slices x 256 rows x 512 e = 4 MB) then emb (512 KB)
    float* part = (float*)d_ws;
    float* emb  = part + (size_t)NSLICE * B_ * H_ * E_;

    dim3 g1(E_ / 128, B_ / 4, (H_ / 4) * NSLICE);  // (4,4,32) = 512 blocks
    k_emb_part<<<g1, 256, 0, stream>>>(x, W_v, (float2*)part);

    k_reduce<<<(B_ * H_ * E_ / 4) / 256, 256, 0, stream>>>((const float4*)part,
                                                           (float4*)emb);

    dim3 g3(E_ / NT, (B_ * H_) / MT);  // (16,16) = 256 blocks
    k_mlp<<<g3, 256, 0, stream>>>(emb, mlp_w, mlp_b, out);
}

// Round 3
// 112.793 us; speedup vs baseline: 1.6074x; 1.0931x over previous
//
#include <hip/hip_runtime.h>
#include <hip/hip_bf16.h>

// Problem constants (reference: B,H,I,E = 16,16,512,512)
#define B_ 16
#define H_ 16
#define I_ 512
#define E_ 512

// Algebraic collapse (verified rounds 1-2, absmax 0.125):
//   softmax(axis=2) followed by sum(axis=2) makes attention exact identity on V:
//   emb[b,h,e] = sum_i x[b,i,e] * W_v[h,i,e];  out = emb @ mlp_w^T + mlp_b.

#define NSLICE 16   // i-slices for k_emb (32 i's each)
#define KSPLIT 8    // k-split for k_mlp (64 k's each)

// ---------------------------------------------------------------------------
// Kernel 1: partial emb with 8x8 register blocking.
// Block: 8 b's x 8 h's x 64 e's (lane=e), one slice of 32 i's split 8/wave.
// Grid (E/64=8, B/8=2, (H/8=2)*16 slices=32) = 512 blocks, 256 threads.
// Logical traffic: x and Wv each read (16/8)=2x -> 64 MB, mostly L3.
// 64 fma per 16 loads per i (vs 64/16... 4 fma/load, double round-2 tile).
// ---------------------------------------------------------------------------
__global__ __launch_bounds__(256) void k_emb_part(const float* __restrict__ x,
                                                  const float* __restrict__ Wv,
                                                  float* __restrict__ part) {
    const int e     = blockIdx.x * 64 + (threadIdx.x & 63);
    const int b0    = blockIdx.y * 8;
    const int h0    = (blockIdx.z & 1) * 8;
    const int slice = blockIdx.z >> 1;        // 0..15
    const int lane  = threadIdx.x & 63;
    const int wave  = threadIdx.x >> 6;       // 0..3

    float acc[8][8];
#pragma unroll
    for (int bi = 0; bi < 8; ++bi)
#pragma unroll
        for (int hj = 0; hj < 8; ++hj) acc[bi][hj] = 0.0f;

    const int ibase = slice * 32 + wave * 8;
    const float* xp[8];
    const float* wp[8];
#pragma unroll
    for (int bi = 0; bi < 8; ++bi)
        xp[bi] = x + ((size_t)(b0 + bi) * I_ + ibase) * E_ + e;
#pragma unroll
    for (int hj = 0; hj < 8; ++hj)
        wp[hj] = Wv + ((size_t)(h0 + hj) * I_ + ibase) * E_ + e;

    for (int ii = 0; ii < 8; ++ii) {
        const int off = ii * E_;
        float xv[8], wv[8];
#pragma unroll
        for (int bi = 0; bi < 8; ++bi) xv[bi] = xp[bi][off];
#pragma unroll
        for (int hj = 0; hj < 8; ++hj) wv[hj] = wp[hj][off];
#pragma unroll
        for (int bi = 0; bi < 8; ++bi)
#pragma unroll
            for (int hj = 0; hj < 8; ++hj)
                acc[bi][hj] = fmaf(xv[bi], wv[hj], acc[bi][hj]);
    }

    // cross-wave reduce (4 i-subslices) through LDS; all accesses stride-1 in
    // lane -> conflict-free.
    __shared__ float red[4][64][64];  // 64 KB -> 2 blocks/CU
#pragma unroll
    for (int bi = 0; bi < 8; ++bi)
#pragma unroll
        for (int hj = 0; hj < 8; ++hj)
            red[wave][bi * 8 + hj][lane] = acc[bi][hj];
    __syncthreads();

    for (int t = threadIdx.x; t < 64 * 64; t += 256) {
        const int pair = t >> 6, le = t & 63;
        float s = (red[0][pair][le] + red[1][pair][le]) +
                  (red[2][pair][le] + red[3][pair][le]);
        const int row = (b0 + (pair >> 3)) * H_ + h0 + (pair & 7);
        part[((size_t)slice * (B_ * H_) + row) * E_ + blockIdx.x * 64 + le] = s;
    }
}

// ---------------------------------------------------------------------------
// Kernel 2: emb = sum of NSLICE partial slices (float4 lanes).
// 256*512/4 = 32768 float4 -> 128 blocks x 256 threads.
// ---------------------------------------------------------------------------
__global__ __launch_bounds__(256) void k_emb_reduce(const float4* __restrict__ part,
                                                    float4* __restrict__ emb) {
    const int idx = blockIdx.x * 256 + threadIdx.x;
    const int sl  = (B_ * H_ * E_) / 4;
    float4 s = part[idx];
#pragma unroll
    for (int j = 1; j < NSLICE; ++j) {
        float4 p = part[(size_t)j * sl + idx];
        s.x += p.x; s.y += p.y; s.z += p.z; s.w += p.w;
    }
    emb[idx] = s;
}

// ---------------------------------------------------------------------------
// Kernel 3: K-split GEMM partials. out-tile 32r x 64c, k-chunk 64, 4x4 micro.
// Grid (512/64=8, 256/32=8, KSPLIT=8) = 512 blocks, 128 threads.
// A staged [r][k] (pad 68), W staged transposed [k][c] (pad 68): both main-loop
// reads are aligned conflict-free ds_read_b128 (2 instr / 4 outputs / k-quad).
// LDS bytes/fma = 2B -> ~2.6 us floor across 256 CUs.
// ---------------------------------------------------------------------------
__global__ __launch_bounds__(128) void k_mlp_part(const float* __restrict__ emb,
                                                  const float* __restrict__ W,
                                                  float* __restrict__ part) {
    const int cblk = blockIdx.x;   // 64-col tile
    const int rblk = blockIdx.y;   // 32-row tile
    const int k0   = blockIdx.z * 64;

    __shared__ float As[32][68];   // [r][k]  8.7 KB (272B row stride, 16B-mult)
    __shared__ float Ws[64][68];   // [k][c] 17.4 KB

    const int t = threadIdx.x;

    // stage A: 32r x 64k, float4 along k (coalesced), direct b128 LDS store
    {
        const int r8 = t >> 4, kq = t & 15;
#pragma unroll
        for (int it = 0; it < 4; ++it) {
            const int r = r8 + it * 8;
            float4 v = *(const float4*)(emb + (size_t)(rblk * 32 + r) * E_ + k0 + kq * 4);
            *(float4*)&As[r][kq * 4] = v;
        }
    }
    // stage W: 64c x 64k, float4 along k (coalesced), transposed scalar stores
    // (8-way write conflict accepted: 32 instrs/thread, ~0.15us total)
    {
        const int c8 = t >> 4, kq = t & 15;
#pragma unroll
        for (int it = 0; it < 8; ++it) {
            const int c = c8 + it * 8;
            float4 v = *(const float4*)(W + (size_t)(cblk * 64 + c) * E_ + k0 + kq * 4);
            Ws[kq * 4 + 0][c] = v.x;
            Ws[kq * 4 + 1][c] = v.y;
            Ws[kq * 4 + 2][c] = v.z;
            Ws[kq * 4 + 3][c] = v.w;
        }
    }
    __syncthreads();

    const int tx = t & 15, ty = t >> 4;   // c-quad 0..15, r-quad 0..7
    const int c0 = tx * 4, r0 = ty * 4;

    float4 acc0 = {0, 0, 0, 0}, acc1 = {0, 0, 0, 0};
    float4 acc2 = {0, 0, 0, 0}, acc3 = {0, 0, 0, 0};

    for (int k = 0; k < 64; k += 4) {
        float4 a0 = *(const float4*)&As[r0 + 0][k];
        float4 a1 = *(const float4*)&As[r0 + 1][k];
        float4 a2 = *(const float4*)&As[r0 + 2][k];
        float4 a3 = *(const float4*)&As[r0 + 3][k];
        float4 w0 = *(const float4*)&Ws[k + 0][c0];
        float4 w1 = *(const float4*)&Ws[k + 1][c0];
        float4 w2 = *(const float4*)&Ws[k + 2][c0];
        float4 w3 = *(const float4*)&Ws[k + 3][c0];
#define MLP_STEP(ACC, AV)                                                  \
        ACC.x = fmaf(AV.x, w0.x, fmaf(AV.y, w1.x, fmaf(AV.z, w2.x, fmaf(AV.w, w3.x, ACC.x)))); \
        ACC.y = fmaf(AV.x, w0.y, fmaf(AV.y, w1.y, fmaf(AV.z, w2.y, fmaf(AV.w, w3.y, ACC.y)))); \
        ACC.z = fmaf(AV.x, w0.z, fmaf(AV.y, w1.z, fmaf(AV.z, w2.z, fmaf(AV.w, w3.z, ACC.z)))); \
        ACC.w = fmaf(AV.x, w0.w, fmaf(AV.y, w1.w, fmaf(AV.z, w2.w, fmaf(AV.w, w3.w, ACC.w))));
        MLP_STEP(acc0, a0)
        MLP_STEP(acc1, a1)
        MLP_STEP(acc2, a2)
        MLP_STEP(acc3, a3)
#undef MLP_STEP
    }

    float* dst = part + ((size_t)blockIdx.z * (B_ * H_) + rblk * 32 + r0) * E_ +
                 cblk * 64 + c0;
    *(float4*)(dst + 0 * E_) = acc0;
    *(float4*)(dst + 1 * E_) = acc1;
    *(float4*)(dst + 2 * E_) = acc2;
    *(float4*)(dst + 3 * E_) = acc3;
}

// ---------------------------------------------------------------------------
// Kernel 4: out = sum of KSPLIT partials + bias. 128 blocks x 256 threads.
// ---------------------------------------------------------------------------
__global__ __launch_bounds__(256) void k_out(const float4* __restrict__ part,
                                             const float4* __restrict__ bias,
                                             float4* __restrict__ out) {
    const int idx = blockIdx.x * 256 + threadIdx.x;   // < 32768
    const int sl  = (B_ * H_ * E_) / 4;
    float4 s = part[idx];
#pragma unroll
    for (int j = 1; j < KSPLIT; ++j) {
        float4 p = part[(size_t)j * sl + idx];
        s.x += p.x; s.y += p.y; s.z += p.z; s.w += p.w;
    }
    float4 bv = bias[idx & (E_ / 4 - 1)];
    s.x += bv.x; s.y += bv.y; s.z += bv.z; s.w += bv.w;
    out[idx] = s;
}

extern "C" void kernel_launch(void* const* d_in, const int* in_sizes, int n_in,
                              void* d_out, int out_size, void* d_ws, size_t ws_size,
                              hipStream_t stream) {
    // setup_inputs order: x, W_q, W_k, W_v, mlp_w, mlp_b  (all fp32)
    const float* x     = (const float*)d_in[0];
    const float* W_v   = (const float*)d_in[3];
    const float* mlp_w = (const float*)d_in[4];
    const float* mlp_b = (const float*)d_in[5];
    float* out = (float*)d_out;

    // ws layout: emb partials (16 x 256 x 512 = 8 MB) | emb (512 KB) |
    //            mlp partials (8 x 256 x 512 = 4 MB)
    float* epart = (float*)d_ws;
    float* emb   = epart + (size_t)NSLICE * B_ * H_ * E_;
    float* mpart = emb + (size_t)B_ * H_ * E_;

    dim3 g1(E_ / 64, B_ / 8, (H_ / 8) * NSLICE);   // (8,2,32) = 512 blocks
    k_emb_part<<<g1, 256, 0, stream>>>(x, W_v, epart);

    k_emb_reduce<<<(B_ * H_ * E_ / 4) / 256, 256, 0, stream>>>(
        (const float4*)epart, (float4*)emb);

    dim3 g3(E_ / 64, (B_ * H_) / 32, KSPLIT);      // (8,8,8) = 512 blocks
    k_mlp_part<<<g3, 128, 0, stream>>>(emb, mlp_w, mpart);

    k_out<<<(B_ * H_ * E_ / 4) / 256, 256, 0, stream>>>(
        (const float4*)mpart, (const float4*)mlp_b, (float4*)out);
}